// Round 5
// baseline (719.166 us; speedup 1.0000x reference)
//
#include <hip/hip_runtime.h>
#include <hip/hip_bf16.h>
#include <math.h>

#define B_ 2
#define CIN 256
#define D_ 128
#define N_ 8192
#define SPLITS 2
#define KVB 64

typedef unsigned short u16;
typedef __attribute__((ext_vector_type(8))) short short8;   // 16 B = 8 bf16
typedef __attribute__((ext_vector_type(4))) short short4v;  // 8 B = 4 bf16
typedef __attribute__((ext_vector_type(4))) float f32x4;

#define NEG_BIG (-1.0e30f)

__device__ __forceinline__ u16 f2bf(float f) {
  union { float f; unsigned u; } v; v.f = f;
  unsigned r = v.u + 0x7fffu + ((v.u >> 16) & 1u);
  return (u16)(r >> 16);
}
__device__ __forceinline__ float bf2f(u16 h) {
  union { unsigned u; float f; } v; v.u = ((unsigned)h) << 16;
  return v.f;
}
__device__ __forceinline__ float expclamp(float x) {
  // sentinel-fed exponentials: clamp so any exp lowering is NaN-free
  return __expf(fmaxf(x, -80.0f));
}
__device__ __forceinline__ f32x4 mfma16(short8 a, short8 b, f32x4 c) {
  return __builtin_amdgcn_mfma_f32_16x16x32_bf16(a, b, c, 0, 0, 0);
}

// ---------------------------------------------------------------------------
// Kernel 1: fused projections. Per block: 64 tokens, all 128 outs, 3 projs.
// x [B][256][N] fp32 -> Qg,Kg bf16 [B][N][128], Vtg bf16 [B][128][N]
// ---------------------------------------------------------------------------
__global__ __launch_bounds__(256) void proj_kernel(
    const float* __restrict__ x, const float* __restrict__ g_w,
    const float* __restrict__ g_b, const float* __restrict__ th_w,
    const float* __restrict__ th_b, const float* __restrict__ ph_w,
    const float* __restrict__ ph_b, u16* __restrict__ Qg,
    u16* __restrict__ Kg, u16* __restrict__ Vtg) {
  __shared__ float xs[CIN][64];  // 64 KB, reused as [64][132] staging later
  const int t = threadIdx.x;
  const int b = blockIdx.y;
  const int n0 = blockIdx.x * 64;
  {
    const int n4 = t & 15, cc = t >> 4;
    for (int c = cc; c < CIN; c += 16) {
      const float4 v = *reinterpret_cast<const float4*>(
          x + ((size_t)b * CIN + c) * N_ + n0 + n4 * 4);
      *reinterpret_cast<float4*>(&xs[c][n4 * 4]) = v;
    }
  }
  __syncthreads();
  const int nl = t & 63, o0 = t >> 6;  // lane token, wave's out-channel phase
  float aT[32], aP[32], aG[32];
#pragma unroll
  for (int k = 0; k < 32; ++k) aT[k] = aP[k] = aG[k] = 0.f;
#pragma unroll 4
  for (int c = 0; c < CIN; ++c) {
    const float xv = xs[c][nl];
#pragma unroll
    for (int k = 0; k < 32; ++k) {
      const int o = o0 + 4 * k;  // wave-uniform -> scalar loads of weights
      aG[k] = fmaf(g_w[o * CIN + c], xv, aG[k]);
      aT[k] = fmaf(th_w[o * CIN + c], xv, aT[k]);
      aP[k] = fmaf(ph_w[o * CIN + c], xv, aP[k]);
    }
  }
  __syncthreads();
  float* st = &xs[0][0];  // staging [64][132]
  // theta -> Qg
#pragma unroll
  for (int k = 0; k < 32; ++k)
    st[nl * 132 + o0 + 4 * k] = aT[k] + th_b[o0 + 4 * k];
  __syncthreads();
  for (int i = t; i < 64 * 128; i += 256) {
    const int n = i >> 7, o = i & 127;
    Qg[((size_t)b * N_ + n0 + n) * D_ + o] = f2bf(st[n * 132 + o]);
  }
  __syncthreads();
  // phi -> Kg
#pragma unroll
  for (int k = 0; k < 32; ++k)
    st[nl * 132 + o0 + 4 * k] = aP[k] + ph_b[o0 + 4 * k];
  __syncthreads();
  for (int i = t; i < 64 * 128; i += 256) {
    const int n = i >> 7, o = i & 127;
    Kg[((size_t)b * N_ + n0 + n) * D_ + o] = f2bf(st[n * 132 + o]);
  }
  __syncthreads();
  // g -> Vtg (transposed store: [B][128][N])
#pragma unroll
  for (int k = 0; k < 32; ++k)
    st[nl * 132 + o0 + 4 * k] = aG[k] + g_b[o0 + 4 * k];
  __syncthreads();
  for (int i = t; i < 64 * 128; i += 256) {
    const int o = i >> 6, n = i & 63;
    Vtg[((size_t)b * D_ + o) * N_ + n0 + n] = f2bf(st[n * 132 + o]);
  }
}

// ---------------------------------------------------------------------------
// Kernel 2: flash attention (bf16 MFMA, fp32 online softmax), KV split 2-way.
// 4 waves x 32 q-rows = 128 q-rows per block. KV tile = 64 keys, dbuf LDS.
// Swapped QK^T (mfma(K,Q) -> S^T) distributes each q-row over 4 lanes.
// PV loads A (P) and B (V) fragments with the SAME k-slot->key permutation
// (uniform across lanes), so the contraction is exact independent of k-order.
// Staging uses 16-BYTE short8 per lane: 16 lanes x 8 elem = 128 (K row),
// 8 lanes x 8 elem = 64 (V row) -- every LDS byte of the tile is written.
// ---------------------------------------------------------------------------
__global__ __launch_bounds__(256) void attn_kernel(
    const u16* __restrict__ Qg, const u16* __restrict__ Kg,
    const u16* __restrict__ Vtg, u16* __restrict__ Opart,
    float2* __restrict__ stats) {
  __shared__ __align__(16) u16 Ks[2][KVB][136];  // row stride 272 B (16B mult)
  __shared__ __align__(16) u16 Vs[2][D_][72];    // row stride 144 B (16B mult)
  const int t = threadIdx.x;
  const int wv = t >> 6, lane = t & 63;
  const int l15 = lane & 15, hi = lane >> 4;
  const int qb = blockIdx.x, b = blockIdx.y, sp = blockIdx.z;
  const int q0 = qb * 128 + wv * 32;
  const size_t key0 = (size_t)sp * (N_ / SPLITS);
  const int NT = (N_ / SPLITS) / KVB;

  // hoist Q fragments: qf[qt][ks] = Q[q0+qt*16+l15][ks*32 + hi*8 + 0..7]
  short8 qf[2][4];
#pragma unroll
  for (int qt = 0; qt < 2; ++qt)
#pragma unroll
    for (int ks = 0; ks < 4; ++ks)
      qf[qt][ks] = *reinterpret_cast<const short8*>(
          Qg + ((size_t)b * N_ + q0 + qt * 16 + l15) * D_ + ks * 32 + hi * 8);

  f32x4 oacc[2][8];
#pragma unroll
  for (int qt = 0; qt < 2; ++qt)
#pragma unroll
    for (int ds = 0; ds < 8; ++ds) {
      f32x4 z = {0.f, 0.f, 0.f, 0.f};
      oacc[qt][ds] = z;
    }
  float mrun[2] = {NEG_BIG, NEG_BIG};
  float lrun[2] = {0.f, 0.f};

  const int kr = t >> 4, kseg = t & 15;  // K staging: 16 lanes x 16B = 256B row
  const int vd = t >> 3, vseg = t & 7;   // V staging: 8 lanes x 16B = 128B row

  {  // prologue: stage tile 0 into buf 0
    short8 kv[4], vv[4];
#pragma unroll
    for (int i = 0; i < 4; ++i) {
      kv[i] = *reinterpret_cast<const short8*>(
          Kg + ((size_t)b * N_ + key0 + kr + i * 16) * D_ + kseg * 8);
      vv[i] = *reinterpret_cast<const short8*>(
          Vtg + ((size_t)b * D_ + vd + i * 32) * N_ + key0 + vseg * 8);
    }
#pragma unroll
    for (int i = 0; i < 4; ++i) {
      *reinterpret_cast<short8*>(&Ks[0][kr + i * 16][kseg * 8]) = kv[i];
      *reinterpret_cast<short8*>(&Vs[0][vd + i * 32][vseg * 8]) = vv[i];
    }
  }
  __syncthreads();

  for (int tile = 0; tile < NT; ++tile) {
    const int cur = tile & 1;
    const bool pre = (tile + 1 < NT);
    short8 kv[4], vv[4];
    if (pre) {  // issue next-tile global loads early; they hide under compute
      const size_t kb2 = key0 + (size_t)(tile + 1) * KVB;
#pragma unroll
      for (int i = 0; i < 4; ++i) {
        kv[i] = *reinterpret_cast<const short8*>(
            Kg + ((size_t)b * N_ + kb2 + kr + i * 16) * D_ + kseg * 8);
        vv[i] = *reinterpret_cast<const short8*>(
            Vtg + ((size_t)b * D_ + vd + i * 32) * N_ + kb2 + vseg * 8);
      }
    }
    // S^T = K * Q^T : out col = q (lane&15), row = key (hi*4+reg)
    f32x4 sacc[2][4];
#pragma unroll
    for (int qt = 0; qt < 2; ++qt)
#pragma unroll
      for (int sub = 0; sub < 4; ++sub) {
        f32x4 z = {0.f, 0.f, 0.f, 0.f};
        sacc[qt][sub] = z;
      }
#pragma unroll
    for (int sub = 0; sub < 4; ++sub) {
#pragma unroll
      for (int ks = 0; ks < 4; ++ks) {
        const short8 kf = *reinterpret_cast<const short8*>(
            &Ks[cur][sub * 16 + l15][ks * 32 + hi * 8]);
        sacc[0][sub] = mfma16(kf, qf[0][ks], sacc[0][sub]);
        sacc[1][sub] = mfma16(kf, qf[1][ks], sacc[1][sub]);
      }
    }
    // online softmax per q-subtile (q-row lives on lanes {q, q+16, q+32, q+48})
    short8 paq[2][2];
#pragma unroll
    for (int qt = 0; qt < 2; ++qt) {
      float pmax = NEG_BIG;
#pragma unroll
      for (int sub = 0; sub < 4; ++sub)
#pragma unroll
        for (int r = 0; r < 4; ++r) pmax = fmaxf(pmax, sacc[qt][sub][r]);
      pmax = fmaxf(pmax, __shfl_xor(pmax, 16));
      pmax = fmaxf(pmax, __shfl_xor(pmax, 32));
      const float mnew = fmaxf(mrun[qt], pmax);
      const float scale = expclamp(mrun[qt] - mnew);  // ~0 on first tile
      mrun[qt] = mnew;
      float rs = 0.f;
      float p[4][4];
#pragma unroll
      for (int sub = 0; sub < 4; ++sub)
#pragma unroll
        for (int r = 0; r < 4; ++r) {
          p[sub][r] = __expf(sacc[qt][sub][r] - mnew);  // arg finite, <= 0
          rs += p[sub][r];
        }
      rs += __shfl_xor(rs, 16);
      rs += __shfl_xor(rs, 32);
      lrun[qt] = lrun[qt] * scale + rs;
      // broadcast per-row rescale to O's row layout (row = hi*4+r)
      float osc[4];
#pragma unroll
      for (int r = 0; r < 4; ++r) osc[r] = __shfl(scale, (hi << 2) + r);
#pragma unroll
      for (int ds = 0; ds < 8; ++ds)
#pragma unroll
        for (int r = 0; r < 4; ++r) oacc[qt][ds][r] *= osc[r];
      // P -> bf16 A-fragments; k-slot k=hi*8+j holds key kappa(k):
      //   j<4 -> kb*32 + hi*4+j, j>=4 -> kb*32+16+hi*4+(j-4)  (lane-uniform)
#pragma unroll
      for (int kb = 0; kb < 2; ++kb)
#pragma unroll
        for (int j = 0; j < 4; ++j) {
          paq[qt][kb][j] = (short)f2bf(p[2 * kb][j]);
          paq[qt][kb][4 + j] = (short)f2bf(p[2 * kb + 1][j]);
        }
    }
    // PV: V fragments loaded with the SAME kappa; shared across qt
#pragma unroll
    for (int ds = 0; ds < 8; ++ds) {
#pragma unroll
      for (int kb = 0; kb < 2; ++kb) {
        const short4v v0 = *reinterpret_cast<const short4v*>(
            &Vs[cur][ds * 16 + l15][kb * 32 + hi * 4]);
        const short4v v1 = *reinterpret_cast<const short4v*>(
            &Vs[cur][ds * 16 + l15][kb * 32 + 16 + hi * 4]);
        short8 vf;
        vf[0] = v0[0]; vf[1] = v0[1]; vf[2] = v0[2]; vf[3] = v0[3];
        vf[4] = v1[0]; vf[5] = v1[1]; vf[6] = v1[2]; vf[7] = v1[3];
        oacc[0][ds] = mfma16(paq[0][kb], vf, oacc[0][ds]);
        oacc[1][ds] = mfma16(paq[1][kb], vf, oacc[1][ds]);
      }
    }
    __syncthreads();
    if (pre) {
      const int nxt = cur ^ 1;
#pragma unroll
      for (int i = 0; i < 4; ++i) {
        *reinterpret_cast<short8*>(&Ks[nxt][kr + i * 16][kseg * 8]) = kv[i];
        *reinterpret_cast<short8*>(&Vs[nxt][vd + i * 32][vseg * 8]) = vv[i];
      }
    }
    __syncthreads();
  }
  // epilogue: unnormalized O + (m, l) stats per split
  const size_t ob = (((size_t)sp * B_ + b) * N_) * D_;
#pragma unroll
  for (int qt = 0; qt < 2; ++qt) {
#pragma unroll
    for (int ds = 0; ds < 8; ++ds)
#pragma unroll
      for (int r = 0; r < 4; ++r) {
        const int q = q0 + qt * 16 + hi * 4 + r;
        Opart[ob + (size_t)q * D_ + ds * 16 + l15] = f2bf(oacc[qt][ds][r]);
      }
    if (hi == 0)
      stats[((size_t)sp * B_ + b) * N_ + q0 + qt * 16 + l15] =
          make_float2(mrun[qt], lrun[qt]);
  }
}

// ---------------------------------------------------------------------------
// Kernel 3: combine the 2 KV-splits -> y fp32 [B][N][128]
// ---------------------------------------------------------------------------
__global__ __launch_bounds__(256) void combine_kernel(
    const u16* __restrict__ Opart, const float2* __restrict__ stats,
    float* __restrict__ y) {
  const size_t total = (size_t)B_ * N_ * D_;
  for (size_t i = (size_t)blockIdx.x * 256 + threadIdx.x; i < total;
       i += (size_t)gridDim.x * 256) {
    const size_t bq = i >> 7;
    const float2 s0 = stats[bq];
    const float2 s1 = stats[(size_t)B_ * N_ + bq];
    const float M = fmaxf(s0.x, s1.x);
    const float w0 = expclamp(s0.x - M), w1 = expclamp(s1.x - M);
    const float den = w0 * s0.y + w1 * s1.y;
    const float o0 = bf2f(Opart[i]);
    const float o1 = bf2f(Opart[total + i]);
    y[i] = (w0 * o0 + w1 * o1) / den;
  }
}

// ---------------------------------------------------------------------------
// Kernel 4: out[b,c,n] = sum_d w_w[c,d]*y[b,n,d] + w_b[c] + x[b,c,n]
// ---------------------------------------------------------------------------
__global__ __launch_bounds__(256) void final_kernel(
    const float* __restrict__ y, const float* __restrict__ w_w,
    const float* __restrict__ w_b, const float* __restrict__ x,
    float* __restrict__ out) {
  __shared__ float ys[64][132];
  const int t = threadIdx.x;
  const int b = blockIdx.y;
  const int n0 = blockIdx.x * 64;
  {
    const int seg = t & 31, r0 = t >> 5;
    for (int r = r0; r < 64; r += 8) {
      const float4 v = *reinterpret_cast<const float4*>(
          y + ((size_t)b * N_ + n0 + r) * D_ + seg * 4);
      *reinterpret_cast<float4*>(&ys[r][seg * 4]) = v;
    }
  }
  __syncthreads();
  const int nl = t & 63, c0 = t >> 6;
  float acc[64];
#pragma unroll
  for (int k = 0; k < 64; ++k) acc[k] = 0.f;
#pragma unroll 4
  for (int d = 0; d < 128; ++d) {
    const float yv = ys[nl][d];
#pragma unroll
    for (int k = 0; k < 64; ++k)
      acc[k] = fmaf(w_w[(c0 + 4 * k) * D_ + d], yv, acc[k]);
  }
#pragma unroll
  for (int k = 0; k < 64; ++k) {
    const int c = c0 + 4 * k;
    const size_t o = ((size_t)b * CIN + c) * N_ + n0 + nl;
    out[o] = acc[k] + w_b[c] + x[o];
  }
}

extern "C" void kernel_launch(void* const* d_in, const int* in_sizes, int n_in,
                              void* d_out, int out_size, void* d_ws,
                              size_t ws_size, hipStream_t stream) {
  const float* x = (const float*)d_in[0];
  const float* g_w = (const float*)d_in[1];
  const float* g_b = (const float*)d_in[2];
  const float* th_w = (const float*)d_in[3];
  const float* th_b = (const float*)d_in[4];
  const float* ph_w = (const float*)d_in[5];
  const float* ph_b = (const float*)d_in[6];
  const float* w_w = (const float*)d_in[7];
  const float* w_b = (const float*)d_in[8];
  float* out = (float*)d_out;

  // ws layout (peak 20.25 MB). y (fp32, 8MB) ALIASES Qg+Kg, which are dead
  // by the time combine_kernel writes y.
  char* ws = (char*)d_ws;
  float* y = (float*)ws;  // overlaps Qg+Kg
  u16* Qg = (u16*)ws;    ws += (size_t)B_ * N_ * D_ * 2;   // 4 MB
  u16* Kg = (u16*)ws;    ws += (size_t)B_ * N_ * D_ * 2;   // 4 MB
  u16* Vtg = (u16*)ws;   ws += (size_t)B_ * N_ * D_ * 2;   // 4 MB
  u16* Opart = (u16*)ws; ws += (size_t)SPLITS * B_ * N_ * D_ * 2;  // 8 MB
  float2* stats = (float2*)ws;                              // 256 KB

  proj_kernel<<<dim3(N_ / 64, B_), 256, 0, stream>>>(
      x, g_w, g_b, th_w, th_b, ph_w, ph_b, Qg, Kg, Vtg);
  attn_kernel<<<dim3(N_ / 128, B_, SPLITS), 256, 0, stream>>>(
      Qg, Kg, Vtg, Opart, stats);
  combine_kernel<<<dim3(2048), 256, 0, stream>>>(Opart, stats, y);
  final_kernel<<<dim3(N_ / 64, B_), 256, 0, stream>>>(y, w_w, w_b, x, out);
}

// Round 10
// 377.237 us; speedup vs baseline: 1.9064x; 1.9064x over previous
//
#include <hip/hip_runtime.h>
#include <hip/hip_bf16.h>
#include <math.h>

#define B_ 2
#define CIN 256
#define D_ 128
#define N_ 8192
#define SPLITS 2
#define KVB 64

typedef unsigned short u16;
typedef unsigned long long u64;
typedef __attribute__((ext_vector_type(8))) short short8;   // 16 B = 8 bf16
typedef __attribute__((ext_vector_type(4))) short short4v;  // 8 B = 4 bf16
typedef __attribute__((ext_vector_type(4))) float f32x4;

#define NEG_BIG (-1.0e30f)

__device__ __forceinline__ u16 f2bf(float f) {
  union { float f; unsigned u; } v; v.f = f;
  unsigned r = v.u + 0x7fffu + ((v.u >> 16) & 1u);
  return (u16)(r >> 16);
}
__device__ __forceinline__ float bf2f(u16 h) {
  union { unsigned u; float f; } v; v.u = ((unsigned)h) << 16;
  return v.f;
}
__device__ __forceinline__ float expclamp(float x) {
  return __expf(fmaxf(x, -80.0f));
}
__device__ __forceinline__ f32x4 mfma16(short8 a, short8 b, f32x4 c) {
  return __builtin_amdgcn_mfma_f32_16x16x32_bf16(a, b, c, 0, 0, 0);
}
__device__ __forceinline__ u64 pack4(float a, float b, float c, float d) {
  return (u64)f2bf(a) | ((u64)f2bf(b) << 16) | ((u64)f2bf(c) << 32) |
         ((u64)f2bf(d) << 48);
}

// ---------------------------------------------------------------------------
// Kernel 0: weights fp32 -> bf16 (192 KB total, stays L2-hot for proj_mfma)
// ---------------------------------------------------------------------------
__global__ __launch_bounds__(256) void wcvt_kernel(
    const float* __restrict__ th_w, const float* __restrict__ ph_w,
    const float* __restrict__ g_w, u16* __restrict__ Wt,
    u16* __restrict__ Wp, u16* __restrict__ Wg) {
  const float* src = blockIdx.y == 0 ? th_w : (blockIdx.y == 1 ? ph_w : g_w);
  u16* dst = blockIdx.y == 0 ? Wt : (blockIdx.y == 1 ? Wp : Wg);
  const int i = (blockIdx.x * 256 + threadIdx.x) * 4;
  const float4 v = *reinterpret_cast<const float4*>(&src[i]);
  *reinterpret_cast<u64*>(&dst[i]) = pack4(v.x, v.y, v.z, v.w);
}

// ---------------------------------------------------------------------------
// Kernel 1: MFMA projections. 512 thr / 8 waves, 64 tokens per block.
// xT LDS tile is bf16, XOR-swizzled (c ^ ((n&7)<<3)) -> stage-writes b64 and
// fragment-reads b128 both sit at the LDS bank floor.
// Wave wv: tokens tg*16..+16 (tg=wv&3), o-half oh*64..+64 (oh=wv>>2).
// Qg/Kg: acc = mfma(wf, xa)  -> D[row=o][col=token]; per-lane 8B store (4 o).
// Vtg:   acc = mfma(xa, wf)  -> D[row=token][col=o]; per-lane 8B store (4 n).
// A and B fragments use the identical lane->(idx,k) pattern (m97-verified),
// so contraction is exact under any internal k-order.
// ---------------------------------------------------------------------------
__global__ __launch_bounds__(512) void proj_mfma(
    const float* __restrict__ x, const u16* __restrict__ Wt,
    const u16* __restrict__ Wp, const u16* __restrict__ Wg,
    const float* __restrict__ th_b, const float* __restrict__ ph_b,
    const float* __restrict__ g_b, u16* __restrict__ Qg,
    u16* __restrict__ Kg, u16* __restrict__ Vtg) {
  __shared__ __align__(16) u16 xT[64][256];  // 32 KB, [n][c ^ ((n&7)<<3)]
  const int t = threadIdx.x;
  const int b = blockIdx.y, n0 = blockIdx.x * 64;
  {  // stage: wave wv covers all 64 tokens for c = it*32 + wv*4 .. +4
    const int n = t & 63, ph = t >> 6;
#pragma unroll
    for (int it = 0; it < 8; ++it) {
      const int c0 = it * 32 + ph * 4;
      const size_t base = ((size_t)b * CIN + c0) * N_ + n0 + n;
      const float v0 = x[base];
      const float v1 = x[base + N_];
      const float v2 = x[base + 2 * N_];
      const float v3 = x[base + 3 * N_];
      const int cs = c0 ^ ((n & 7) << 3);
      *reinterpret_cast<u64*>(&xT[n][cs]) = pack4(v0, v1, v2, v3);
    }
  }
  __syncthreads();

  const int lane = t & 63, wv = t >> 6;
  const int l15 = lane & 15, hi = lane >> 4;
  const int tg = wv & 3, oh = wv >> 2;
  const int nrow = tg * 16 + l15;

  short8 xa[8];
#pragma unroll
  for (int ks = 0; ks < 8; ++ks) {
    const int c = (ks * 32 + hi * 8) ^ ((nrow & 7) << 3);
    xa[ks] = *reinterpret_cast<const short8*>(&xT[nrow][c]);
  }

  // theta -> Qg, phi -> Kg
  const size_t qrow = ((size_t)b * N_ + n0 + tg * 16 + l15) * D_;
#pragma unroll
  for (int pp = 0; pp < 2; ++pp) {
    const u16* W = pp ? Wp : Wt;
    const float* bias = pp ? ph_b : th_b;
    u16* out = pp ? Kg : Qg;
#pragma unroll
    for (int os = 0; os < 4; ++os) {
      const int ob = oh * 64 + os * 16;
      short8 wf[8];
#pragma unroll
      for (int ks = 0; ks < 8; ++ks)
        wf[ks] = *reinterpret_cast<const short8*>(
            &W[(size_t)(ob + l15) * CIN + ks * 32 + hi * 8]);
      f32x4 acc = {0.f, 0.f, 0.f, 0.f};
#pragma unroll
      for (int ks = 0; ks < 8; ++ks) acc = mfma16(wf[ks], xa[ks], acc);
      const float4 bb = *reinterpret_cast<const float4*>(&bias[ob + hi * 4]);
      *reinterpret_cast<u64*>(&out[qrow + ob + hi * 4]) =
          pack4(acc[0] + bb.x, acc[1] + bb.y, acc[2] + bb.z, acc[3] + bb.w);
    }
  }
  // g -> Vtg (transposed output)
#pragma unroll
  for (int os = 0; os < 4; ++os) {
    const int ob = oh * 64 + os * 16;
    short8 wf[8];
#pragma unroll
    for (int ks = 0; ks < 8; ++ks)
      wf[ks] = *reinterpret_cast<const short8*>(
          &Wg[(size_t)(ob + l15) * CIN + ks * 32 + hi * 8]);
    f32x4 acc = {0.f, 0.f, 0.f, 0.f};
#pragma unroll
    for (int ks = 0; ks < 8; ++ks) acc = mfma16(xa[ks], wf[ks], acc);
    const float bs = g_b[ob + l15];
    *reinterpret_cast<u64*>(
        &Vtg[((size_t)b * D_ + ob + l15) * N_ + n0 + tg * 16 + hi * 4]) =
        pack4(acc[0] + bs, acc[1] + bs, acc[2] + bs, acc[3] + bs);
  }
}

// ---------------------------------------------------------------------------
// Kernel 2: flash attention (unchanged from round 5 -- passed, absmax 0.031)
// ---------------------------------------------------------------------------
__global__ __launch_bounds__(256) void attn_kernel(
    const u16* __restrict__ Qg, const u16* __restrict__ Kg,
    const u16* __restrict__ Vtg, u16* __restrict__ Opart,
    float2* __restrict__ stats) {
  __shared__ __align__(16) u16 Ks[2][KVB][136];
  __shared__ __align__(16) u16 Vs[2][D_][72];
  const int t = threadIdx.x;
  const int wv = t >> 6, lane = t & 63;
  const int l15 = lane & 15, hi = lane >> 4;
  const int qb = blockIdx.x, b = blockIdx.y, sp = blockIdx.z;
  const int q0 = qb * 128 + wv * 32;
  const size_t key0 = (size_t)sp * (N_ / SPLITS);
  const int NT = (N_ / SPLITS) / KVB;

  short8 qf[2][4];
#pragma unroll
  for (int qt = 0; qt < 2; ++qt)
#pragma unroll
    for (int ks = 0; ks < 4; ++ks)
      qf[qt][ks] = *reinterpret_cast<const short8*>(
          Qg + ((size_t)b * N_ + q0 + qt * 16 + l15) * D_ + ks * 32 + hi * 8);

  f32x4 oacc[2][8];
#pragma unroll
  for (int qt = 0; qt < 2; ++qt)
#pragma unroll
    for (int ds = 0; ds < 8; ++ds) {
      f32x4 z = {0.f, 0.f, 0.f, 0.f};
      oacc[qt][ds] = z;
    }
  float mrun[2] = {NEG_BIG, NEG_BIG};
  float lrun[2] = {0.f, 0.f};

  const int kr = t >> 4, kseg = t & 15;
  const int vd = t >> 3, vseg = t & 7;

  {
    short8 kv[4], vv[4];
#pragma unroll
    for (int i = 0; i < 4; ++i) {
      kv[i] = *reinterpret_cast<const short8*>(
          Kg + ((size_t)b * N_ + key0 + kr + i * 16) * D_ + kseg * 8);
      vv[i] = *reinterpret_cast<const short8*>(
          Vtg + ((size_t)b * D_ + vd + i * 32) * N_ + key0 + vseg * 8);
    }
#pragma unroll
    for (int i = 0; i < 4; ++i) {
      *reinterpret_cast<short8*>(&Ks[0][kr + i * 16][kseg * 8]) = kv[i];
      *reinterpret_cast<short8*>(&Vs[0][vd + i * 32][vseg * 8]) = vv[i];
    }
  }
  __syncthreads();

  for (int tile = 0; tile < NT; ++tile) {
    const int cur = tile & 1;
    const bool pre = (tile + 1 < NT);
    short8 kv[4], vv[4];
    if (pre) {
      const size_t kb2 = key0 + (size_t)(tile + 1) * KVB;
#pragma unroll
      for (int i = 0; i < 4; ++i) {
        kv[i] = *reinterpret_cast<const short8*>(
            Kg + ((size_t)b * N_ + kb2 + kr + i * 16) * D_ + kseg * 8);
        vv[i] = *reinterpret_cast<const short8*>(
            Vtg + ((size_t)b * D_ + vd + i * 32) * N_ + kb2 + vseg * 8);
      }
    }
    f32x4 sacc[2][4];
#pragma unroll
    for (int qt = 0; qt < 2; ++qt)
#pragma unroll
      for (int sub = 0; sub < 4; ++sub) {
        f32x4 z = {0.f, 0.f, 0.f, 0.f};
        sacc[qt][sub] = z;
      }
#pragma unroll
    for (int sub = 0; sub < 4; ++sub) {
#pragma unroll
      for (int ks = 0; ks < 4; ++ks) {
        const short8 kf = *reinterpret_cast<const short8*>(
            &Ks[cur][sub * 16 + l15][ks * 32 + hi * 8]);
        sacc[0][sub] = mfma16(kf, qf[0][ks], sacc[0][sub]);
        sacc[1][sub] = mfma16(kf, qf[1][ks], sacc[1][sub]);
      }
    }
    short8 paq[2][2];
#pragma unroll
    for (int qt = 0; qt < 2; ++qt) {
      float pmax = NEG_BIG;
#pragma unroll
      for (int sub = 0; sub < 4; ++sub)
#pragma unroll
        for (int r = 0; r < 4; ++r) pmax = fmaxf(pmax, sacc[qt][sub][r]);
      pmax = fmaxf(pmax, __shfl_xor(pmax, 16));
      pmax = fmaxf(pmax, __shfl_xor(pmax, 32));
      const float mnew = fmaxf(mrun[qt], pmax);
      const float scale = expclamp(mrun[qt] - mnew);
      mrun[qt] = mnew;
      float rs = 0.f;
      float p[4][4];
#pragma unroll
      for (int sub = 0; sub < 4; ++sub)
#pragma unroll
        for (int r = 0; r < 4; ++r) {
          p[sub][r] = __expf(sacc[qt][sub][r] - mnew);
          rs += p[sub][r];
        }
      rs += __shfl_xor(rs, 16);
      rs += __shfl_xor(rs, 32);
      lrun[qt] = lrun[qt] * scale + rs;
      float osc[4];
#pragma unroll
      for (int r = 0; r < 4; ++r) osc[r] = __shfl(scale, (hi << 2) + r);
#pragma unroll
      for (int ds = 0; ds < 8; ++ds)
#pragma unroll
        for (int r = 0; r < 4; ++r) oacc[qt][ds][r] *= osc[r];
#pragma unroll
      for (int kb = 0; kb < 2; ++kb)
#pragma unroll
        for (int j = 0; j < 4; ++j) {
          paq[qt][kb][j] = (short)f2bf(p[2 * kb][j]);
          paq[qt][kb][4 + j] = (short)f2bf(p[2 * kb + 1][j]);
        }
    }
#pragma unroll
    for (int ds = 0; ds < 8; ++ds) {
#pragma unroll
      for (int kb = 0; kb < 2; ++kb) {
        const short4v v0 = *reinterpret_cast<const short4v*>(
            &Vs[cur][ds * 16 + l15][kb * 32 + hi * 4]);
        const short4v v1 = *reinterpret_cast<const short4v*>(
            &Vs[cur][ds * 16 + l15][kb * 32 + 16 + hi * 4]);
        short8 vf;
        vf[0] = v0[0]; vf[1] = v0[1]; vf[2] = v0[2]; vf[3] = v0[3];
        vf[4] = v1[0]; vf[5] = v1[1]; vf[6] = v1[2]; vf[7] = v1[3];
        oacc[0][ds] = mfma16(paq[0][kb], vf, oacc[0][ds]);
        oacc[1][ds] = mfma16(paq[1][kb], vf, oacc[1][ds]);
      }
    }
    __syncthreads();
    if (pre) {
      const int nxt = cur ^ 1;
#pragma unroll
      for (int i = 0; i < 4; ++i) {
        *reinterpret_cast<short8*>(&Ks[nxt][kr + i * 16][kseg * 8]) = kv[i];
        *reinterpret_cast<short8*>(&Vs[nxt][vd + i * 32][vseg * 8]) = vv[i];
      }
    }
    __syncthreads();
  }
  const size_t ob = (((size_t)sp * B_ + b) * N_) * D_;
#pragma unroll
  for (int qt = 0; qt < 2; ++qt) {
#pragma unroll
    for (int ds = 0; ds < 8; ++ds)
#pragma unroll
      for (int r = 0; r < 4; ++r) {
        const int q = q0 + qt * 16 + hi * 4 + r;
        Opart[ob + (size_t)q * D_ + ds * 16 + l15] = f2bf(oacc[qt][ds][r]);
      }
    if (hi == 0)
      stats[((size_t)sp * B_ + b) * N_ + q0 + qt * 16 + l15] =
          make_float2(mrun[qt], lrun[qt]);
  }
}

// ---------------------------------------------------------------------------
// Kernel 3: combine the 2 KV-splits -> y fp32 [B][N][128]
// ---------------------------------------------------------------------------
__global__ __launch_bounds__(256) void combine_kernel(
    const u16* __restrict__ Opart, const float2* __restrict__ stats,
    float* __restrict__ y) {
  const size_t total = (size_t)B_ * N_ * D_;
  for (size_t i = (size_t)blockIdx.x * 256 + threadIdx.x; i < total;
       i += (size_t)gridDim.x * 256) {
    const size_t bq = i >> 7;
    const float2 s0 = stats[bq];
    const float2 s1 = stats[(size_t)B_ * N_ + bq];
    const float M = fmaxf(s0.x, s1.x);
    const float w0 = expclamp(s0.x - M), w1 = expclamp(s1.x - M);
    const float den = w0 * s0.y + w1 * s1.y;
    const float o0 = bf2f(Opart[i]);
    const float o1 = bf2f(Opart[total + i]);
    y[i] = (w0 * o0 + w1 * o1) / den;
  }
}

// ---------------------------------------------------------------------------
// Kernel 4: out[b,c,n] = sum_d w_w[c,d]*y[b,n,d] + w_b[c] + x[b,c,n]
// ---------------------------------------------------------------------------
__global__ __launch_bounds__(256) void final_kernel(
    const float* __restrict__ y, const float* __restrict__ w_w,
    const float* __restrict__ w_b, const float* __restrict__ x,
    float* __restrict__ out) {
  __shared__ float ys[64][132];
  const int t = threadIdx.x;
  const int b = blockIdx.y;
  const int n0 = blockIdx.x * 64;
  {
    const int seg = t & 31, r0 = t >> 5;
    for (int r = r0; r < 64; r += 8) {
      const float4 v = *reinterpret_cast<const float4*>(
          y + ((size_t)b * N_ + n0 + r) * D_ + seg * 4);
      *reinterpret_cast<float4*>(&ys[r][seg * 4]) = v;
    }
  }
  __syncthreads();
  const int nl = t & 63, c0 = t >> 6;
  float acc[64];
#pragma unroll
  for (int k = 0; k < 64; ++k) acc[k] = 0.f;
#pragma unroll 4
  for (int d = 0; d < 128; ++d) {
    const float yv = ys[nl][d];
#pragma unroll
    for (int k = 0; k < 64; ++k)
      acc[k] = fmaf(w_w[(c0 + 4 * k) * D_ + d], yv, acc[k]);
  }
#pragma unroll
  for (int k = 0; k < 64; ++k) {
    const int c = c0 + 4 * k;
    const size_t o = ((size_t)b * CIN + c) * N_ + n0 + nl;
    out[o] = acc[k] + w_b[c] + x[o];
  }
}

extern "C" void kernel_launch(void* const* d_in, const int* in_sizes, int n_in,
                              void* d_out, int out_size, void* d_ws,
                              size_t ws_size, hipStream_t stream) {
  const float* x = (const float*)d_in[0];
  const float* g_w = (const float*)d_in[1];
  const float* g_b = (const float*)d_in[2];
  const float* th_w = (const float*)d_in[3];
  const float* th_b = (const float*)d_in[4];
  const float* ph_w = (const float*)d_in[5];
  const float* ph_b = (const float*)d_in[6];
  const float* w_w = (const float*)d_in[7];
  const float* w_b = (const float*)d_in[8];
  float* out = (float*)d_out;

  // ws layout (~20.7 MB peak). y (fp32, 8MB) aliases Qg+Kg (dead by then).
  char* ws = (char*)d_ws;
  float* y = (float*)ws;  // overlaps Qg+Kg
  u16* Qg = (u16*)ws;    ws += (size_t)B_ * N_ * D_ * 2;   // 4 MB
  u16* Kg = (u16*)ws;    ws += (size_t)B_ * N_ * D_ * 2;   // 4 MB
  u16* Vtg = (u16*)ws;   ws += (size_t)B_ * N_ * D_ * 2;   // 4 MB
  u16* Opart = (u16*)ws; ws += (size_t)SPLITS * B_ * N_ * D_ * 2;  // 8 MB
  float2* stats = (float2*)ws; ws += (size_t)SPLITS * B_ * N_ * sizeof(float2);
  u16* Wt = (u16*)ws;    ws += (size_t)128 * 256 * 2;       // 64 KB
  u16* Wp = (u16*)ws;    ws += (size_t)128 * 256 * 2;
  u16* Wg = (u16*)ws;    ws += (size_t)128 * 256 * 2;

  wcvt_kernel<<<dim3(32, 3), 256, 0, stream>>>(th_w, ph_w, g_w, Wt, Wp, Wg);
  proj_mfma<<<dim3(N_ / 64, B_), 512, 0, stream>>>(
      x, Wt, Wp, Wg, th_b, ph_b, g_b, Qg, Kg, Vtg);
  attn_kernel<<<dim3(N_ / 128, B_, SPLITS), 256, 0, stream>>>(
      Qg, Kg, Vtg, Opart, stats);
  combine_kernel<<<dim3(2048), 256, 0, stream>>>(Opart, stats, y);
  final_kernel<<<dim3(N_ / 64, B_), 256, 0, stream>>>(y, w_w, w_b, x, out);
}

// Round 11
// 276.161 us; speedup vs baseline: 2.6042x; 1.3660x over previous
//
#include <hip/hip_runtime.h>
#include <hip/hip_bf16.h>
#include <math.h>

#define B_ 2
#define CIN 256
#define D_ 128
#define N_ 8192
#define SPLITS 2
#define KVB 64

typedef unsigned short u16;
typedef unsigned long long u64;
typedef __attribute__((ext_vector_type(8))) short short8;   // 16 B = 8 bf16
typedef __attribute__((ext_vector_type(4))) short short4v;  // 8 B = 4 bf16
typedef __attribute__((ext_vector_type(4))) float f32x4;

#define NEG_BIG (-1.0e30f)

__device__ __forceinline__ u16 f2bf(float f) {
  union { float f; unsigned u; } v; v.f = f;
  unsigned r = v.u + 0x7fffu + ((v.u >> 16) & 1u);
  return (u16)(r >> 16);
}
__device__ __forceinline__ float bf2f(u16 h) {
  union { unsigned u; float f; } v; v.u = ((unsigned)h) << 16;
  return v.f;
}
__device__ __forceinline__ float expclamp(float x) {
  return __expf(fmaxf(x, -80.0f));
}
__device__ __forceinline__ f32x4 mfma16(short8 a, short8 b, f32x4 c) {
  return __builtin_amdgcn_mfma_f32_16x16x32_bf16(a, b, c, 0, 0, 0);
}
__device__ __forceinline__ u64 pack4(float a, float b, float c, float d) {
  return (u64)f2bf(a) | ((u64)f2bf(b) << 16) | ((u64)f2bf(c) << 32) |
         ((u64)f2bf(d) << 48);
}

// ---------------------------------------------------------------------------
// Kernel 0: weights fp32 -> bf16 (th, ph, g: 128x256; w_w: 256x128 -- all
// 32768 elements). 256 KB total, stays L2-hot.
// ---------------------------------------------------------------------------
__global__ __launch_bounds__(256) void wcvt_kernel(
    const float* __restrict__ th_w, const float* __restrict__ ph_w,
    const float* __restrict__ g_w, const float* __restrict__ w_w,
    u16* __restrict__ Wt, u16* __restrict__ Wp, u16* __restrict__ Wg,
    u16* __restrict__ Wm) {
  const int s = blockIdx.y;
  const float* src = s == 0 ? th_w : (s == 1 ? ph_w : (s == 2 ? g_w : w_w));
  u16* dst = s == 0 ? Wt : (s == 1 ? Wp : (s == 2 ? Wg : Wm));
  const int i = (blockIdx.x * 256 + threadIdx.x) * 4;
  const float4 v = *reinterpret_cast<const float4*>(&src[i]);
  *reinterpret_cast<u64*>(&dst[i]) = pack4(v.x, v.y, v.z, v.w);
}

// ---------------------------------------------------------------------------
// Kernel 1: MFMA projections (validated r10: 719->377 us, absmax unchanged).
// ---------------------------------------------------------------------------
__global__ __launch_bounds__(512) void proj_mfma(
    const float* __restrict__ x, const u16* __restrict__ Wt,
    const u16* __restrict__ Wp, const u16* __restrict__ Wg,
    const float* __restrict__ th_b, const float* __restrict__ ph_b,
    const float* __restrict__ g_b, u16* __restrict__ Qg,
    u16* __restrict__ Kg, u16* __restrict__ Vtg) {
  __shared__ __align__(16) u16 xT[64][256];  // 32 KB, [n][c ^ ((n&7)<<3)]
  const int t = threadIdx.x;
  const int b = blockIdx.y, n0 = blockIdx.x * 64;
  {
    const int n = t & 63, ph = t >> 6;
#pragma unroll
    for (int it = 0; it < 8; ++it) {
      const int c0 = it * 32 + ph * 4;
      const size_t base = ((size_t)b * CIN + c0) * N_ + n0 + n;
      const float v0 = x[base];
      const float v1 = x[base + N_];
      const float v2 = x[base + 2 * N_];
      const float v3 = x[base + 3 * N_];
      const int cs = c0 ^ ((n & 7) << 3);
      *reinterpret_cast<u64*>(&xT[n][cs]) = pack4(v0, v1, v2, v3);
    }
  }
  __syncthreads();

  const int lane = t & 63, wv = t >> 6;
  const int l15 = lane & 15, hi = lane >> 4;
  const int tg = wv & 3, oh = wv >> 2;
  const int nrow = tg * 16 + l15;

  short8 xa[8];
#pragma unroll
  for (int ks = 0; ks < 8; ++ks) {
    const int c = (ks * 32 + hi * 8) ^ ((nrow & 7) << 3);
    xa[ks] = *reinterpret_cast<const short8*>(&xT[nrow][c]);
  }

  const size_t qrow = ((size_t)b * N_ + n0 + tg * 16 + l15) * D_;
#pragma unroll
  for (int pp = 0; pp < 2; ++pp) {
    const u16* W = pp ? Wp : Wt;
    const float* bias = pp ? ph_b : th_b;
    u16* out = pp ? Kg : Qg;
#pragma unroll
    for (int os = 0; os < 4; ++os) {
      const int ob = oh * 64 + os * 16;
      short8 wf[8];
#pragma unroll
      for (int ks = 0; ks < 8; ++ks)
        wf[ks] = *reinterpret_cast<const short8*>(
            &W[(size_t)(ob + l15) * CIN + ks * 32 + hi * 8]);
      f32x4 acc = {0.f, 0.f, 0.f, 0.f};
#pragma unroll
      for (int ks = 0; ks < 8; ++ks) acc = mfma16(wf[ks], xa[ks], acc);
      const float4 bb = *reinterpret_cast<const float4*>(&bias[ob + hi * 4]);
      *reinterpret_cast<u64*>(&out[qrow + ob + hi * 4]) =
          pack4(acc[0] + bb.x, acc[1] + bb.y, acc[2] + bb.z, acc[3] + bb.w);
    }
  }
#pragma unroll
  for (int os = 0; os < 4; ++os) {
    const int ob = oh * 64 + os * 16;
    short8 wf[8];
#pragma unroll
    for (int ks = 0; ks < 8; ++ks)
      wf[ks] = *reinterpret_cast<const short8*>(
          &Wg[(size_t)(ob + l15) * CIN + ks * 32 + hi * 8]);
    f32x4 acc = {0.f, 0.f, 0.f, 0.f};
#pragma unroll
    for (int ks = 0; ks < 8; ++ks) acc = mfma16(xa[ks], wf[ks], acc);
    const float bs = g_b[ob + l15];
    *reinterpret_cast<u64*>(
        &Vtg[((size_t)b * D_ + ob + l15) * N_ + n0 + tg * 16 + hi * 4]) =
        pack4(acc[0] + bs, acc[1] + bs, acc[2] + bs, acc[3] + bs);
  }
}

// ---------------------------------------------------------------------------
// Kernel 2: flash attention (unchanged -- passed r5/r10, absmax 0.031)
// ---------------------------------------------------------------------------
__global__ __launch_bounds__(256) void attn_kernel(
    const u16* __restrict__ Qg, const u16* __restrict__ Kg,
    const u16* __restrict__ Vtg, u16* __restrict__ Opart,
    float2* __restrict__ stats) {
  __shared__ __align__(16) u16 Ks[2][KVB][136];
  __shared__ __align__(16) u16 Vs[2][D_][72];
  const int t = threadIdx.x;
  const int wv = t >> 6, lane = t & 63;
  const int l15 = lane & 15, hi = lane >> 4;
  const int qb = blockIdx.x, b = blockIdx.y, sp = blockIdx.z;
  const int q0 = qb * 128 + wv * 32;
  const size_t key0 = (size_t)sp * (N_ / SPLITS);
  const int NT = (N_ / SPLITS) / KVB;

  short8 qf[2][4];
#pragma unroll
  for (int qt = 0; qt < 2; ++qt)
#pragma unroll
    for (int ks = 0; ks < 4; ++ks)
      qf[qt][ks] = *reinterpret_cast<const short8*>(
          Qg + ((size_t)b * N_ + q0 + qt * 16 + l15) * D_ + ks * 32 + hi * 8);

  f32x4 oacc[2][8];
#pragma unroll
  for (int qt = 0; qt < 2; ++qt)
#pragma unroll
    for (int ds = 0; ds < 8; ++ds) {
      f32x4 z = {0.f, 0.f, 0.f, 0.f};
      oacc[qt][ds] = z;
    }
  float mrun[2] = {NEG_BIG, NEG_BIG};
  float lrun[2] = {0.f, 0.f};

  const int kr = t >> 4, kseg = t & 15;
  const int vd = t >> 3, vseg = t & 7;

  {
    short8 kv[4], vv[4];
#pragma unroll
    for (int i = 0; i < 4; ++i) {
      kv[i] = *reinterpret_cast<const short8*>(
          Kg + ((size_t)b * N_ + key0 + kr + i * 16) * D_ + kseg * 8);
      vv[i] = *reinterpret_cast<const short8*>(
          Vtg + ((size_t)b * D_ + vd + i * 32) * N_ + key0 + vseg * 8);
    }
#pragma unroll
    for (int i = 0; i < 4; ++i) {
      *reinterpret_cast<short8*>(&Ks[0][kr + i * 16][kseg * 8]) = kv[i];
      *reinterpret_cast<short8*>(&Vs[0][vd + i * 32][vseg * 8]) = vv[i];
    }
  }
  __syncthreads();

  for (int tile = 0; tile < NT; ++tile) {
    const int cur = tile & 1;
    const bool pre = (tile + 1 < NT);
    short8 kv[4], vv[4];
    if (pre) {
      const size_t kb2 = key0 + (size_t)(tile + 1) * KVB;
#pragma unroll
      for (int i = 0; i < 4; ++i) {
        kv[i] = *reinterpret_cast<const short8*>(
            Kg + ((size_t)b * N_ + kb2 + kr + i * 16) * D_ + kseg * 8);
        vv[i] = *reinterpret_cast<const short8*>(
            Vtg + ((size_t)b * D_ + vd + i * 32) * N_ + kb2 + vseg * 8);
      }
    }
    f32x4 sacc[2][4];
#pragma unroll
    for (int qt = 0; qt < 2; ++qt)
#pragma unroll
      for (int sub = 0; sub < 4; ++sub) {
        f32x4 z = {0.f, 0.f, 0.f, 0.f};
        sacc[qt][sub] = z;
      }
#pragma unroll
    for (int sub = 0; sub < 4; ++sub) {
#pragma unroll
      for (int ks = 0; ks < 4; ++ks) {
        const short8 kf = *reinterpret_cast<const short8*>(
            &Ks[cur][sub * 16 + l15][ks * 32 + hi * 8]);
        sacc[0][sub] = mfma16(kf, qf[0][ks], sacc[0][sub]);
        sacc[1][sub] = mfma16(kf, qf[1][ks], sacc[1][sub]);
      }
    }
    short8 paq[2][2];
#pragma unroll
    for (int qt = 0; qt < 2; ++qt) {
      float pmax = NEG_BIG;
#pragma unroll
      for (int sub = 0; sub < 4; ++sub)
#pragma unroll
        for (int r = 0; r < 4; ++r) pmax = fmaxf(pmax, sacc[qt][sub][r]);
      pmax = fmaxf(pmax, __shfl_xor(pmax, 16));
      pmax = fmaxf(pmax, __shfl_xor(pmax, 32));
      const float mnew = fmaxf(mrun[qt], pmax);
      const float scale = expclamp(mrun[qt] - mnew);
      mrun[qt] = mnew;
      float rs = 0.f;
      float p[4][4];
#pragma unroll
      for (int sub = 0; sub < 4; ++sub)
#pragma unroll
        for (int r = 0; r < 4; ++r) {
          p[sub][r] = __expf(sacc[qt][sub][r] - mnew);
          rs += p[sub][r];
        }
      rs += __shfl_xor(rs, 16);
      rs += __shfl_xor(rs, 32);
      lrun[qt] = lrun[qt] * scale + rs;
      float osc[4];
#pragma unroll
      for (int r = 0; r < 4; ++r) osc[r] = __shfl(scale, (hi << 2) + r);
#pragma unroll
      for (int ds = 0; ds < 8; ++ds)
#pragma unroll
        for (int r = 0; r < 4; ++r) oacc[qt][ds][r] *= osc[r];
#pragma unroll
      for (int kb = 0; kb < 2; ++kb)
#pragma unroll
        for (int j = 0; j < 4; ++j) {
          paq[qt][kb][j] = (short)f2bf(p[2 * kb][j]);
          paq[qt][kb][4 + j] = (short)f2bf(p[2 * kb + 1][j]);
        }
    }
#pragma unroll
    for (int ds = 0; ds < 8; ++ds) {
#pragma unroll
      for (int kb = 0; kb < 2; ++kb) {
        const short4v v0 = *reinterpret_cast<const short4v*>(
            &Vs[cur][ds * 16 + l15][kb * 32 + hi * 4]);
        const short4v v1 = *reinterpret_cast<const short4v*>(
            &Vs[cur][ds * 16 + l15][kb * 32 + 16 + hi * 4]);
        short8 vf;
        vf[0] = v0[0]; vf[1] = v0[1]; vf[2] = v0[2]; vf[3] = v0[3];
        vf[4] = v1[0]; vf[5] = v1[1]; vf[6] = v1[2]; vf[7] = v1[3];
        oacc[0][ds] = mfma16(paq[0][kb], vf, oacc[0][ds]);
        oacc[1][ds] = mfma16(paq[1][kb], vf, oacc[1][ds]);
      }
    }
    __syncthreads();
    if (pre) {
      const int nxt = cur ^ 1;
#pragma unroll
      for (int i = 0; i < 4; ++i) {
        *reinterpret_cast<short8*>(&Ks[nxt][kr + i * 16][kseg * 8]) = kv[i];
        *reinterpret_cast<short8*>(&Vs[nxt][vd + i * 32][vseg * 8]) = vv[i];
      }
    }
    __syncthreads();
  }
  const size_t ob = (((size_t)sp * B_ + b) * N_) * D_;
#pragma unroll
  for (int qt = 0; qt < 2; ++qt) {
#pragma unroll
    for (int ds = 0; ds < 8; ++ds)
#pragma unroll
      for (int r = 0; r < 4; ++r) {
        const int q = q0 + qt * 16 + hi * 4 + r;
        Opart[ob + (size_t)q * D_ + ds * 16 + l15] = f2bf(oacc[qt][ds][r]);
      }
    if (hi == 0)
      stats[((size_t)sp * B_ + b) * N_ + q0 + qt * 16 + l15] =
          make_float2(mrun[qt], lrun[qt]);
  }
}

// ---------------------------------------------------------------------------
// Kernel 3: combine the 2 KV-splits -> y bf16 [B][N][128]
// ---------------------------------------------------------------------------
__global__ __launch_bounds__(256) void combine_kernel(
    const u16* __restrict__ Opart, const float2* __restrict__ stats,
    u16* __restrict__ y16) {
  const size_t total = (size_t)B_ * N_ * D_;
  for (size_t i = (size_t)blockIdx.x * 256 + threadIdx.x; i < total;
       i += (size_t)gridDim.x * 256) {
    const size_t bq = i >> 7;
    const float2 s0 = stats[bq];
    const float2 s1 = stats[(size_t)B_ * N_ + bq];
    const float M = fmaxf(s0.x, s1.x);
    const float w0 = expclamp(s0.x - M), w1 = expclamp(s1.x - M);
    const float den = w0 * s0.y + w1 * s1.y;
    const float o0 = bf2f(Opart[i]);
    const float o1 = bf2f(Opart[total + i]);
    y16[i] = f2bf((w0 * o0 + w1 * o1) / den);
  }
}

// ---------------------------------------------------------------------------
// Kernel 4: MFMA output projection + bias + residual.
// out[b,c,n] = sum_d Wm[c,d]*y16[b,n,d] + w_b[c] + x[b,c,n]
// Same recipe as proj_mfma's Vtg path: mfma(xa, wf) -> D[row=token][col=c];
// per-lane float4 store over 4 consecutive n. 512 thr / 8 waves.
// ---------------------------------------------------------------------------
__global__ __launch_bounds__(512) void final_mfma(
    const u16* __restrict__ y16, const u16* __restrict__ Wm,
    const float* __restrict__ w_b, const float* __restrict__ x,
    float* __restrict__ out) {
  __shared__ __align__(16) u16 yT[64][128];  // 16 KB, [n][d ^ ((n&7)<<3)]
  const int t = threadIdx.x;
  const int b = blockIdx.y, n0 = blockIdx.x * 64;
  {
    const int dseg = t & 15, nb = t >> 4;  // 32 rows per pass, 2 passes
#pragma unroll
    for (int it = 0; it < 2; ++it) {
      const int nn = nb + it * 32;
      const short8 v = *reinterpret_cast<const short8*>(
          &y16[((size_t)b * N_ + n0 + nn) * D_ + dseg * 8]);
      *reinterpret_cast<short8*>(&yT[nn][(dseg * 8) ^ ((nn & 7) << 3)]) = v;
    }
  }
  __syncthreads();
  const int lane = t & 63, wv = t >> 6;
  const int l15 = lane & 15, hi = lane >> 4;
  const int tg = wv & 3, oh = wv >> 2;
  const int nrow = tg * 16 + l15;

  short8 xa[4];
#pragma unroll
  for (int ks = 0; ks < 4; ++ks) {
    const int c = (ks * 32 + hi * 8) ^ ((nrow & 7) << 3);
    xa[ks] = *reinterpret_cast<const short8*>(&yT[nrow][c]);
  }
#pragma unroll
  for (int os = 0; os < 8; ++os) {
    const int ob = oh * 128 + os * 16;
    short8 wf[4];
#pragma unroll
    for (int ks = 0; ks < 4; ++ks)
      wf[ks] = *reinterpret_cast<const short8*>(
          &Wm[(size_t)(ob + l15) * D_ + ks * 32 + hi * 8]);
    f32x4 acc = {0.f, 0.f, 0.f, 0.f};
#pragma unroll
    for (int ks = 0; ks < 4; ++ks) acc = mfma16(xa[ks], wf[ks], acc);
    const int c = ob + l15;
    const float bs = w_b[c];
    const size_t o = ((size_t)b * CIN + c) * N_ + n0 + tg * 16 + hi * 4;
    const float4 xr = *reinterpret_cast<const float4*>(&x[o]);
    float4 r;
    r.x = acc[0] + bs + xr.x;
    r.y = acc[1] + bs + xr.y;
    r.z = acc[2] + bs + xr.z;
    r.w = acc[3] + bs + xr.w;
    *reinterpret_cast<float4*>(&out[o]) = r;
  }
}

extern "C" void kernel_launch(void* const* d_in, const int* in_sizes, int n_in,
                              void* d_out, int out_size, void* d_ws,
                              size_t ws_size, hipStream_t stream) {
  const float* x = (const float*)d_in[0];
  const float* g_w = (const float*)d_in[1];
  const float* g_b = (const float*)d_in[2];
  const float* th_w = (const float*)d_in[3];
  const float* th_b = (const float*)d_in[4];
  const float* ph_w = (const float*)d_in[5];
  const float* ph_b = (const float*)d_in[6];
  const float* w_w = (const float*)d_in[7];
  const float* w_b = (const float*)d_in[8];
  float* out = (float*)d_out;

  // ws layout (~20.8 MB peak). y16 (bf16, 4MB) aliases Qg (dead by then).
  char* ws = (char*)d_ws;
  u16* y16 = (u16*)ws;   // overlaps Qg
  u16* Qg = (u16*)ws;    ws += (size_t)B_ * N_ * D_ * 2;   // 4 MB
  u16* Kg = (u16*)ws;    ws += (size_t)B_ * N_ * D_ * 2;   // 4 MB
  u16* Vtg = (u16*)ws;   ws += (size_t)B_ * N_ * D_ * 2;   // 4 MB
  u16* Opart = (u16*)ws; ws += (size_t)SPLITS * B_ * N_ * D_ * 2;  // 8 MB
  float2* stats = (float2*)ws; ws += (size_t)SPLITS * B_ * N_ * sizeof(float2);
  u16* Wt = (u16*)ws;    ws += (size_t)128 * 256 * 2;       // 64 KB
  u16* Wp = (u16*)ws;    ws += (size_t)128 * 256 * 2;
  u16* Wg = (u16*)ws;    ws += (size_t)128 * 256 * 2;
  u16* Wm = (u16*)ws;    ws += (size_t)256 * 128 * 2;       // 64 KB

  wcvt_kernel<<<dim3(32, 4), 256, 0, stream>>>(th_w, ph_w, g_w, w_w,
                                               Wt, Wp, Wg, Wm);
  proj_mfma<<<dim3(N_ / 64, B_), 512, 0, stream>>>(
      x, Wt, Wp, Wg, th_b, ph_b, g_b, Qg, Kg, Vtg);
  attn_kernel<<<dim3(N_ / 128, B_, SPLITS), 256, 0, stream>>>(
      Qg, Kg, Vtg, Opart, stats);
  combine_kernel<<<dim3(2048), 256, 0, stream>>>(Opart, stats, y16);
  final_mfma<<<dim3(N_ / 64, B_), 512, 0, stream>>>(y16, Wm, w_b, x, out);
}

// Round 12
// 262.093 us; speedup vs baseline: 2.7439x; 1.0537x over previous
//
#include <hip/hip_runtime.h>
#include <hip/hip_bf16.h>
#include <math.h>

#define B_ 2
#define CIN 256
#define D_ 128
#define N_ 8192
#define SPLITS 2
#define KVB 64

typedef unsigned short u16;
typedef unsigned long long u64;
typedef __attribute__((ext_vector_type(8))) short short8;   // 16 B = 8 bf16
typedef __attribute__((ext_vector_type(4))) short short4v;  // 8 B = 4 bf16
typedef __attribute__((ext_vector_type(4))) float f32x4;

#define NEG_BIG (-1.0e30f)

__device__ __forceinline__ u16 f2bf(float f) {
  union { float f; unsigned u; } v; v.f = f;
  unsigned r = v.u + 0x7fffu + ((v.u >> 16) & 1u);
  return (u16)(r >> 16);
}
__device__ __forceinline__ float bf2f(u16 h) {
  union { unsigned u; float f; } v; v.u = ((unsigned)h) << 16;
  return v.f;
}
__device__ __forceinline__ float expclamp(float x) {
  return __expf(fmaxf(x, -80.0f));
}
__device__ __forceinline__ f32x4 mfma16(short8 a, short8 b, f32x4 c) {
  return __builtin_amdgcn_mfma_f32_16x16x32_bf16(a, b, c, 0, 0, 0);
}
__device__ __forceinline__ u64 pack4(float a, float b, float c, float d) {
  return (u64)f2bf(a) | ((u64)f2bf(b) << 16) | ((u64)f2bf(c) << 32) |
         ((u64)f2bf(d) << 48);
}

// ---------------------------------------------------------------------------
// Kernel 0: weights fp32 -> bf16 (256 KB total, stays L2-hot)
// ---------------------------------------------------------------------------
__global__ __launch_bounds__(256) void wcvt_kernel(
    const float* __restrict__ th_w, const float* __restrict__ ph_w,
    const float* __restrict__ g_w, const float* __restrict__ w_w,
    u16* __restrict__ Wt, u16* __restrict__ Wp, u16* __restrict__ Wg,
    u16* __restrict__ Wm) {
  const int s = blockIdx.y;
  const float* src = s == 0 ? th_w : (s == 1 ? ph_w : (s == 2 ? g_w : w_w));
  u16* dst = s == 0 ? Wt : (s == 1 ? Wp : (s == 2 ? Wg : Wm));
  const int i = (blockIdx.x * 256 + threadIdx.x) * 4;
  const float4 v = *reinterpret_cast<const float4*>(&src[i]);
  *reinterpret_cast<u64*>(&dst[i]) = pack4(v.x, v.y, v.z, v.w);
}

// ---------------------------------------------------------------------------
// Kernel 1: MFMA projections (validated r10)
// ---------------------------------------------------------------------------
__global__ __launch_bounds__(512) void proj_mfma(
    const float* __restrict__ x, const u16* __restrict__ Wt,
    const u16* __restrict__ Wp, const u16* __restrict__ Wg,
    const float* __restrict__ th_b, const float* __restrict__ ph_b,
    const float* __restrict__ g_b, u16* __restrict__ Qg,
    u16* __restrict__ Kg, u16* __restrict__ Vtg) {
  __shared__ __align__(16) u16 xT[64][256];  // 32 KB, [n][c ^ ((n&7)<<3)]
  const int t = threadIdx.x;
  const int b = blockIdx.y, n0 = blockIdx.x * 64;
  {
    const int n = t & 63, ph = t >> 6;
#pragma unroll
    for (int it = 0; it < 8; ++it) {
      const int c0 = it * 32 + ph * 4;
      const size_t base = ((size_t)b * CIN + c0) * N_ + n0 + n;
      const float v0 = x[base];
      const float v1 = x[base + N_];
      const float v2 = x[base + 2 * N_];
      const float v3 = x[base + 3 * N_];
      const int cs = c0 ^ ((n & 7) << 3);
      *reinterpret_cast<u64*>(&xT[n][cs]) = pack4(v0, v1, v2, v3);
    }
  }
  __syncthreads();

  const int lane = t & 63, wv = t >> 6;
  const int l15 = lane & 15, hi = lane >> 4;
  const int tg = wv & 3, oh = wv >> 2;
  const int nrow = tg * 16 + l15;

  short8 xa[8];
#pragma unroll
  for (int ks = 0; ks < 8; ++ks) {
    const int c = (ks * 32 + hi * 8) ^ ((nrow & 7) << 3);
    xa[ks] = *reinterpret_cast<const short8*>(&xT[nrow][c]);
  }

  const size_t qrow = ((size_t)b * N_ + n0 + tg * 16 + l15) * D_;
#pragma unroll
  for (int pp = 0; pp < 2; ++pp) {
    const u16* W = pp ? Wp : Wt;
    const float* bias = pp ? ph_b : th_b;
    u16* out = pp ? Kg : Qg;
#pragma unroll
    for (int os = 0; os < 4; ++os) {
      const int ob = oh * 64 + os * 16;
      short8 wf[8];
#pragma unroll
      for (int ks = 0; ks < 8; ++ks)
        wf[ks] = *reinterpret_cast<const short8*>(
            &W[(size_t)(ob + l15) * CIN + ks * 32 + hi * 8]);
      f32x4 acc = {0.f, 0.f, 0.f, 0.f};
#pragma unroll
      for (int ks = 0; ks < 8; ++ks) acc = mfma16(wf[ks], xa[ks], acc);
      const float4 bb = *reinterpret_cast<const float4*>(&bias[ob + hi * 4]);
      *reinterpret_cast<u64*>(&out[qrow + ob + hi * 4]) =
          pack4(acc[0] + bb.x, acc[1] + bb.y, acc[2] + bb.z, acc[3] + bb.w);
    }
  }
#pragma unroll
  for (int os = 0; os < 4; ++os) {
    const int ob = oh * 64 + os * 16;
    short8 wf[8];
#pragma unroll
    for (int ks = 0; ks < 8; ++ks)
      wf[ks] = *reinterpret_cast<const short8*>(
          &Wg[(size_t)(ob + l15) * CIN + ks * 32 + hi * 8]);
    f32x4 acc = {0.f, 0.f, 0.f, 0.f};
#pragma unroll
    for (int ks = 0; ks < 8; ++ks) acc = mfma16(xa[ks], wf[ks], acc);
    const float bs = g_b[ob + l15];
    *reinterpret_cast<u64*>(
        &Vtg[((size_t)b * D_ + ob + l15) * N_ + n0 + tg * 16 + hi * 4]) =
        pack4(acc[0] + bs, acc[1] + bs, acc[2] + bs, acc[3] + bs);
  }
}

// ---------------------------------------------------------------------------
// Kernel 2: flash attention -- 512 thr / 8 waves, 16 q-rows per wave.
// Same 128-row block, same LDS; doubles waves/CU (4->8) so softmax VALU of
// one wave hides MFMA/stalls of another (m114: separate pipes co-schedule).
// ---------------------------------------------------------------------------
__global__ __launch_bounds__(512) void attn_kernel(
    const u16* __restrict__ Qg, const u16* __restrict__ Kg,
    const u16* __restrict__ Vtg, u16* __restrict__ Opart,
    float2* __restrict__ stats) {
  __shared__ __align__(16) u16 Ks[2][KVB][136];
  __shared__ __align__(16) u16 Vs[2][D_][72];
  const int t = threadIdx.x;
  const int wv = t >> 6, lane = t & 63;
  const int l15 = lane & 15, hi = lane >> 4;
  const int qb = blockIdx.x, b = blockIdx.y, sp = blockIdx.z;
  const int q0 = qb * 128 + wv * 16;
  const size_t key0 = (size_t)sp * (N_ / SPLITS);
  const int NT = (N_ / SPLITS) / KVB;

  // Q fragments for this wave's 16 rows
  short8 qf[4];
#pragma unroll
  for (int ks = 0; ks < 4; ++ks)
    qf[ks] = *reinterpret_cast<const short8*>(
        Qg + ((size_t)b * N_ + q0 + l15) * D_ + ks * 32 + hi * 8);

  f32x4 oacc[8];
#pragma unroll
  for (int ds = 0; ds < 8; ++ds) {
    f32x4 z = {0.f, 0.f, 0.f, 0.f};
    oacc[ds] = z;
  }
  float mrun = NEG_BIG, lrun = 0.f;

  // staging: 1024 slots each for K (64r x 16seg) and V (128r x 8seg);
  // 512 threads x 2 iterations.
  {
    short8 kv[2], vv[2];
#pragma unroll
    for (int it = 0; it < 2; ++it) {
      const int ks_ = it * 512 + t, vs_ = it * 512 + t;
      kv[it] = *reinterpret_cast<const short8*>(
          Kg + ((size_t)b * N_ + key0 + (ks_ >> 4)) * D_ + (ks_ & 15) * 8);
      vv[it] = *reinterpret_cast<const short8*>(
          Vtg + ((size_t)b * D_ + (vs_ >> 3)) * N_ + key0 + (vs_ & 7) * 8);
    }
#pragma unroll
    for (int it = 0; it < 2; ++it) {
      const int ks_ = it * 512 + t, vs_ = it * 512 + t;
      *reinterpret_cast<short8*>(&Ks[0][ks_ >> 4][(ks_ & 15) * 8]) = kv[it];
      *reinterpret_cast<short8*>(&Vs[0][vs_ >> 3][(vs_ & 7) * 8]) = vv[it];
    }
  }
  __syncthreads();

  for (int tile = 0; tile < NT; ++tile) {
    const int cur = tile & 1;
    const bool pre = (tile + 1 < NT);
    short8 kv[2], vv[2];
    if (pre) {
      const size_t kb2 = key0 + (size_t)(tile + 1) * KVB;
#pragma unroll
      for (int it = 0; it < 2; ++it) {
        const int ks_ = it * 512 + t, vs_ = it * 512 + t;
        kv[it] = *reinterpret_cast<const short8*>(
            Kg + ((size_t)b * N_ + kb2 + (ks_ >> 4)) * D_ + (ks_ & 15) * 8);
        vv[it] = *reinterpret_cast<const short8*>(
            Vtg + ((size_t)b * D_ + (vs_ >> 3)) * N_ + kb2 + (vs_ & 7) * 8);
      }
    }
    // S^T = K * Q^T : col = q (l15), row = key (sub*16 + hi*4 + r)
    f32x4 sacc[4];
#pragma unroll
    for (int sub = 0; sub < 4; ++sub) {
      f32x4 z = {0.f, 0.f, 0.f, 0.f};
      sacc[sub] = z;
    }
#pragma unroll
    for (int sub = 0; sub < 4; ++sub) {
#pragma unroll
      for (int ks = 0; ks < 4; ++ks) {
        const short8 kf = *reinterpret_cast<const short8*>(
            &Ks[cur][sub * 16 + l15][ks * 32 + hi * 8]);
        sacc[sub] = mfma16(kf, qf[ks], sacc[sub]);
      }
    }
    // online softmax (q-row on lanes {q, q+16, q+32, q+48})
    float pmax = NEG_BIG;
#pragma unroll
    for (int sub = 0; sub < 4; ++sub)
#pragma unroll
      for (int r = 0; r < 4; ++r) pmax = fmaxf(pmax, sacc[sub][r]);
    pmax = fmaxf(pmax, __shfl_xor(pmax, 16));
    pmax = fmaxf(pmax, __shfl_xor(pmax, 32));
    const float mnew = fmaxf(mrun, pmax);
    const float scale = expclamp(mrun - mnew);
    mrun = mnew;
    float rs = 0.f;
    float p[4][4];
#pragma unroll
    for (int sub = 0; sub < 4; ++sub)
#pragma unroll
      for (int r = 0; r < 4; ++r) {
        p[sub][r] = __expf(sacc[sub][r] - mnew);
        rs += p[sub][r];
      }
    rs += __shfl_xor(rs, 16);
    rs += __shfl_xor(rs, 32);
    lrun = lrun * scale + rs;
    float osc[4];
#pragma unroll
    for (int r = 0; r < 4; ++r) osc[r] = __shfl(scale, (hi << 2) + r);
#pragma unroll
    for (int ds = 0; ds < 8; ++ds)
#pragma unroll
      for (int r = 0; r < 4; ++r) oacc[ds][r] *= osc[r];
    // P -> bf16 A-frags; k-slot hi*8+j holds key kb*32 + (j<4 ? hi*4+j
    // : 16+hi*4+j-4) -- lane-uniform permutation shared with V below.
    short8 paq[2];
#pragma unroll
    for (int kb = 0; kb < 2; ++kb)
#pragma unroll
      for (int j = 0; j < 4; ++j) {
        paq[kb][j] = (short)f2bf(p[2 * kb][j]);
        paq[kb][4 + j] = (short)f2bf(p[2 * kb + 1][j]);
      }
    // PV with identical key permutation on B
#pragma unroll
    for (int ds = 0; ds < 8; ++ds) {
#pragma unroll
      for (int kb = 0; kb < 2; ++kb) {
        const short4v v0 = *reinterpret_cast<const short4v*>(
            &Vs[cur][ds * 16 + l15][kb * 32 + hi * 4]);
        const short4v v1 = *reinterpret_cast<const short4v*>(
            &Vs[cur][ds * 16 + l15][kb * 32 + 16 + hi * 4]);
        short8 vf;
        vf[0] = v0[0]; vf[1] = v0[1]; vf[2] = v0[2]; vf[3] = v0[3];
        vf[4] = v1[0]; vf[5] = v1[1]; vf[6] = v1[2]; vf[7] = v1[3];
        oacc[ds] = mfma16(paq[kb], vf, oacc[ds]);
      }
    }
    __syncthreads();
    if (pre) {
      const int nxt = cur ^ 1;
#pragma unroll
      for (int it = 0; it < 2; ++it) {
        const int ks_ = it * 512 + t, vs_ = it * 512 + t;
        *reinterpret_cast<short8*>(&Ks[nxt][ks_ >> 4][(ks_ & 15) * 8]) = kv[it];
        *reinterpret_cast<short8*>(&Vs[nxt][vs_ >> 3][(vs_ & 7) * 8]) = vv[it];
      }
    }
    __syncthreads();
  }
  // epilogue
  const size_t ob = (((size_t)sp * B_ + b) * N_) * D_;
#pragma unroll
  for (int ds = 0; ds < 8; ++ds)
#pragma unroll
    for (int r = 0; r < 4; ++r) {
      const int q = q0 + hi * 4 + r;
      Opart[ob + (size_t)q * D_ + ds * 16 + l15] = f2bf(oacc[ds][r]);
    }
  if (hi == 0)
    stats[((size_t)sp * B_ + b) * N_ + q0 + l15] = make_float2(mrun, lrun);
}

// ---------------------------------------------------------------------------
// Kernel 3: combine the 2 KV-splits -> y bf16 [B][N][128]
// ---------------------------------------------------------------------------
__global__ __launch_bounds__(256) void combine_kernel(
    const u16* __restrict__ Opart, const float2* __restrict__ stats,
    u16* __restrict__ y16) {
  const size_t total = (size_t)B_ * N_ * D_;
  for (size_t i = (size_t)blockIdx.x * 256 + threadIdx.x; i < total;
       i += (size_t)gridDim.x * 256) {
    const size_t bq = i >> 7;
    const float2 s0 = stats[bq];
    const float2 s1 = stats[(size_t)B_ * N_ + bq];
    const float M = fmaxf(s0.x, s1.x);
    const float w0 = expclamp(s0.x - M), w1 = expclamp(s1.x - M);
    const float den = w0 * s0.y + w1 * s1.y;
    const float o0 = bf2f(Opart[i]);
    const float o1 = bf2f(Opart[total + i]);
    y16[i] = f2bf((w0 * o0 + w1 * o1) / den);
  }
}

// ---------------------------------------------------------------------------
// Kernel 4: MFMA output projection + bias + residual (validated r11)
// ---------------------------------------------------------------------------
__global__ __launch_bounds__(512) void final_mfma(
    const u16* __restrict__ y16, const u16* __restrict__ Wm,
    const float* __restrict__ w_b, const float* __restrict__ x,
    float* __restrict__ out) {
  __shared__ __align__(16) u16 yT[64][128];  // 16 KB, [n][d ^ ((n&7)<<3)]
  const int t = threadIdx.x;
  const int b = blockIdx.y, n0 = blockIdx.x * 64;
  {
    const int dseg = t & 15, nb = t >> 4;
#pragma unroll
    for (int it = 0; it < 2; ++it) {
      const int nn = nb + it * 32;
      const short8 v = *reinterpret_cast<const short8*>(
          &y16[((size_t)b * N_ + n0 + nn) * D_ + dseg * 8]);
      *reinterpret_cast<short8*>(&yT[nn][(dseg * 8) ^ ((nn & 7) << 3)]) = v;
    }
  }
  __syncthreads();
  const int lane = t & 63, wv = t >> 6;
  const int l15 = lane & 15, hi = lane >> 4;
  const int tg = wv & 3, oh = wv >> 2;
  const int nrow = tg * 16 + l15;

  short8 xa[4];
#pragma unroll
  for (int ks = 0; ks < 4; ++ks) {
    const int c = (ks * 32 + hi * 8) ^ ((nrow & 7) << 3);
    xa[ks] = *reinterpret_cast<const short8*>(&yT[nrow][c]);
  }
#pragma unroll
  for (int os = 0; os < 8; ++os) {
    const int ob = oh * 128 + os * 16;
    short8 wf[4];
#pragma unroll
    for (int ks = 0; ks < 4; ++ks)
      wf[ks] = *reinterpret_cast<const short8*>(
          &Wm[(size_t)(ob + l15) * D_ + ks * 32 + hi * 8]);
    f32x4 acc = {0.f, 0.f, 0.f, 0.f};
#pragma unroll
    for (int ks = 0; ks < 4; ++ks) acc = mfma16(xa[ks], wf[ks], acc);
    const int c = ob + l15;
    const float bs = w_b[c];
    const size_t o = ((size_t)b * CIN + c) * N_ + n0 + tg * 16 + hi * 4;
    const float4 xr = *reinterpret_cast<const float4*>(&x[o]);
    float4 r;
    r.x = acc[0] + bs + xr.x;
    r.y = acc[1] + bs + xr.y;
    r.z = acc[2] + bs + xr.z;
    r.w = acc[3] + bs + xr.w;
    *reinterpret_cast<float4*>(&out[o]) = r;
  }
}

extern "C" void kernel_launch(void* const* d_in, const int* in_sizes, int n_in,
                              void* d_out, int out_size, void* d_ws,
                              size_t ws_size, hipStream_t stream) {
  const float* x = (const float*)d_in[0];
  const float* g_w = (const float*)d_in[1];
  const float* g_b = (const float*)d_in[2];
  const float* th_w = (const float*)d_in[3];
  const float* th_b = (const float*)d_in[4];
  const float* ph_w = (const float*)d_in[5];
  const float* ph_b = (const float*)d_in[6];
  const float* w_w = (const float*)d_in[7];
  const float* w_b = (const float*)d_in[8];
  float* out = (float*)d_out;

  // ws layout (~20.8 MB peak). y16 (bf16, 4MB) aliases Qg (dead by then).
  char* ws = (char*)d_ws;
  u16* y16 = (u16*)ws;   // overlaps Qg
  u16* Qg = (u16*)ws;    ws += (size_t)B_ * N_ * D_ * 2;   // 4 MB
  u16* Kg = (u16*)ws;    ws += (size_t)B_ * N_ * D_ * 2;   // 4 MB
  u16* Vtg = (u16*)ws;   ws += (size_t)B_ * N_ * D_ * 2;   // 4 MB
  u16* Opart = (u16*)ws; ws += (size_t)SPLITS * B_ * N_ * D_ * 2;  // 8 MB
  float2* stats = (float2*)ws; ws += (size_t)SPLITS * B_ * N_ * sizeof(float2);
  u16* Wt = (u16*)ws;    ws += (size_t)128 * 256 * 2;       // 64 KB
  u16* Wp = (u16*)ws;    ws += (size_t)128 * 256 * 2;
  u16* Wg = (u16*)ws;    ws += (size_t)128 * 256 * 2;
  u16* Wm = (u16*)ws;    ws += (size_t)256 * 128 * 2;       // 64 KB

  wcvt_kernel<<<dim3(32, 4), 256, 0, stream>>>(th_w, ph_w, g_w, w_w,
                                               Wt, Wp, Wg, Wm);
  proj_mfma<<<dim3(N_ / 64, B_), 512, 0, stream>>>(
      x, Wt, Wp, Wg, th_b, ph_b, g_b, Qg, Kg, Vtg);
  attn_kernel<<<dim3(N_ / 128, B_, SPLITS), 512, 0, stream>>>(
      Qg, Kg, Vtg, Opart, stats);
  combine_kernel<<<dim3(2048), 256, 0, stream>>>(Opart, stats, y16);
  final_mfma<<<dim3(N_ / 64, B_), 512, 0, stream>>>(y16, Wm, w_b, x, out);
}